// Round 12
// baseline (199.183 us; speedup 1.0000x reference)
//
#include <hip/hip_runtime.h>
#include <hip/hip_bf16.h>

// MHA block: x[4096,1024] fp32; Wq/Wk/Wv/Wo [1024,1024] fp32.
// R22: attn = 4 q-chunks x 2 key-halves (64 q-rows/wave, 2 waves/SIMD).
//  Pipe audit: both GEMM and attn are LDS-read-pipe limited (GEMM: 192
//  b128 x 12cyc + writes = 3074 ~= 3100 wall). Only lever: more output per
//  fragment read. R13 proved 64q/wave halves LDS reads but died at
//  1 wave/SIMD. Fix (legal because this softmax has NO running max -> l and
//  oacc are linear in keys): waves 0-3 process keys 0..2047, waves 4-7 keys
//  2048..4095, each with 64 q-rows; partials merged in LDS at the end.
//  Per 128 keys: LDS reads 256 -> 128 (1536cyc <= MFMA 2794) -> MFMA-bound.
//  Same proven 1-barrier/step skeleton, stage->read program order kept
//  (the conservative-drain correctness mechanism). 4 tile streams, 64KB.
//  Merge epilogue: hi waves write oacc (stride-68 padded, conflict-free)
//  + l to LDS; lo waves add, scale by 1/l, store.
// GEMM/cast/launcher: R16 verbatim (R21 static-vmcnt pipeline was flat ->
//  GEMM sync experiments closed).

typedef __bf16 bf16_t;
typedef __bf16 bf16x8 __attribute__((ext_vector_type(8)));
typedef __bf16 bf16x4 __attribute__((ext_vector_type(4)));
typedef float f32x4 __attribute__((ext_vector_type(4)));

#define D_MODEL 1024
#define SEQ 4096
#define HEADS 16
#define DK 64
#define QSCALE 0.1803368801111204f  // log2(e)/8
#define EXP2_MAGIC 8404859.0f       // 2^23 + 16251 (integer-exact float)

// ---------------- fused casts fp32 -> bf16 ----------------
__global__ void cast_all(const float* __restrict__ x, const float* __restrict__ a,
                         const float* __restrict__ b, const float* __restrict__ c,
                         const float* __restrict__ d, bf16_t* __restrict__ xb,
                         bf16_t* __restrict__ wb) {
    const int gi = blockIdx.x * blockDim.x + threadIdx.x;
    const float* src; bf16_t* dst; int i;
    if (gi < SEQ * D_MODEL / 4) {
        src = x; dst = xb; i = gi * 4;
    } else {
        int g = gi - SEQ * D_MODEL / 4;
        int which = g >> 18;
        src = which == 0 ? a : which == 1 ? b : which == 2 ? c : d;
        dst = wb + (size_t)which * D_MODEL * D_MODEL;
        i = (g & 0x3FFFF) * 4;
    }
    float4 v = *(const float4*)(src + i);
    bf16x4 o;
    o[0] = (bf16_t)v.x; o[1] = (bf16_t)v.y; o[2] = (bf16_t)v.z; o[3] = (bf16_t)v.w;
    *(bf16x4*)(dst + i) = o;
}

__device__ __forceinline__ void g2l16(const bf16_t* g, bf16_t* l) {
    __builtin_amdgcn_global_load_lds(
        (const __attribute__((address_space(1))) void*)g,
        (__attribute__((address_space(3))) void*)l, 16, 0, 0);
}

// Schraudolph exp2 -> packed bf16x8: slots 0-3 = 2^a[r], 4-7 = 2^b[r].
__device__ __forceinline__ bf16x8 exp2_pk(const f32x4 a, const f32x4 b) {
    union { float f; unsigned u; } v[8];
#pragma unroll
    for (int r = 0; r < 4; r++) {
        v[r].f     = fmaf(a[r], 128.0f, EXP2_MAGIC);
        v[r + 4].f = fmaf(b[r], 128.0f, EXP2_MAGIC);
    }
    union { unsigned u[4]; bf16x8 h; } o;
#pragma unroll
    for (int p = 0; p < 4; p++)
        o.u[p] = __builtin_amdgcn_perm(v[2 * p + 1].u, v[2 * p].u, 0x05040100u);
    return o.h;
}

// ---------------- LDS-staged NT GEMM, 128x128 tile, XCD swizzle ----------
// (R16 verbatim.) ROUTE 1: QKV split; V^T written key-interleaved.
template <int ROUTE>
__global__ __launch_bounds__(256, 2) void gemm_lds(const bf16_t* __restrict__ A,
                                                   const bf16_t* __restrict__ B,
                                                   void* __restrict__ out0,
                                                   void* __restrict__ out1,
                                                   void* __restrict__ out2,
                                                   int M, int N, int K) {
    __shared__ __align__(16) bf16_t As[128 * 64];
    __shared__ __align__(16) bf16_t Bs[128 * 64];

    const int tid = threadIdx.x;
    const int lane = tid & 63;
    const int wave = tid >> 6;
    const int l15 = lane & 15;
    const int lg  = lane >> 4;

    const int flat = blockIdx.y * gridDim.x + blockIdx.x;
    const int mpx  = gridDim.y >> 3;
    const int xcd  = flat & 7;
    const int pos  = flat >> 3;
    const int m0 = (xcd * mpx + (pos % mpx)) * 128;
    const int n0 = (pos / mpx) * 128;
    const int wm = (wave >> 1) * 64;
    const int wn = (wave & 1) * 64;

    const bf16_t* aSrc[4]; bf16_t* aDst[4];
    const bf16_t* bSrc[4]; bf16_t* bDst[4];
#pragma unroll
    for (int it = 0; it < 4; it++) {
        int c = it * 256 + tid;
        int row = c >> 3, cc = (c & 7) ^ (row & 7);
        aSrc[it] = A + (size_t)(m0 + row) * K + cc * 8;
        aDst[it] = As + c * 8;
        bSrc[it] = B + (size_t)(n0 + row) * K + cc * 8;
        bDst[it] = Bs + c * 8;
    }

    int aoff[2][4], boff[2][4];
#pragma unroll
    for (int kk = 0; kk < 2; kk++) {
#pragma unroll
        for (int i = 0; i < 4; i++) {
            int row = wm + i * 16 + l15;
            aoff[kk][i] = row * 64 + (((kk << 2) | lg) ^ (row & 7)) * 8;
        }
#pragma unroll
        for (int j = 0; j < 4; j++) {
            int row = wn + j * 16 + l15;
            boff[kk][j] = row * 64 + (((kk << 2) | lg) ^ (row & 7)) * 8;
        }
    }

    f32x4 acc[4][4];
#pragma unroll
    for (int i = 0; i < 4; i++)
#pragma unroll
        for (int j = 0; j < 4; j++) acc[i][j] = f32x4{0.f, 0.f, 0.f, 0.f};

    for (int k0 = 0; k0 < K; k0 += 64) {
#pragma unroll
        for (int it = 0; it < 4; it++) g2l16(aSrc[it] + k0, aDst[it]);
#pragma unroll
        for (int it = 0; it < 4; it++) g2l16(bSrc[it] + k0, bDst[it]);
        __syncthreads();

#pragma unroll
        for (int kk = 0; kk < 2; kk++) {
            bf16x8 af[4], bfm[4];
#pragma unroll
            for (int i = 0; i < 4; i++) af[i] = *(const bf16x8*)(As + aoff[kk][i]);
#pragma unroll
            for (int j = 0; j < 4; j++) bfm[j] = *(const bf16x8*)(Bs + boff[kk][j]);
#pragma unroll
            for (int i = 0; i < 4; i++)
#pragma unroll
                for (int j = 0; j < 4; j++)
                    acc[i][j] = __builtin_amdgcn_mfma_f32_16x16x32_bf16(af[i], bfm[j], acc[i][j], 0, 0, 0);
        }
        __syncthreads();
    }

    const int ng = n0 + wn;  // 64-aligned -> region-uniform per wave
    if (ROUTE == 0) {
        float* C = (float*)out0;
#pragma unroll
        for (int i = 0; i < 4; i++)
#pragma unroll
            for (int r = 0; r < 4; r++) {
                int m = m0 + wm + i * 16 + lg * 4 + r;
                float* crow = C + (size_t)m * N + ng;
#pragma unroll
                for (int j = 0; j < 4; j++) crow[j * 16 + l15] = acc[i][j][r];
            }
    } else {
        if (ng < 2048) {
            const bool isQ = (ng < 1024);
            const float sc = isQ ? QSCALE : 1.0f;
            bf16_t* dst = isQ ? (bf16_t*)out0 : (bf16_t*)out1;
            int nn = ng & 1023;
#pragma unroll
            for (int i = 0; i < 4; i++)
#pragma unroll
                for (int r = 0; r < 4; r++) {
                    int m = m0 + wm + i * 16 + lg * 4 + r;
                    bf16_t* crow = dst + (size_t)m * D_MODEL + nn;
#pragma unroll
                    for (int j = 0; j < 4; j++) crow[j * 16 + l15] = (bf16_t)(acc[i][j][r] * sc);
                }
        } else {
            bf16_t* Vt = (bf16_t*)out2;
#pragma unroll
            for (int i = 0; i < 4; i++)
#pragma unroll
                for (int j = 0; j < 4; j++) {
                    int vcol = ng - 2048 + j * 16 + l15;
                    int m = m0 + wm + i * 16 + lg * 4;  // multiple of 4
                    // key-interleave within 32-key block: pos = g*8 + sub*4 + r
                    int mp = (m & ~31) | (((m >> 2) & 3) << 3) | (((m >> 4) & 1) << 2);
                    bf16x4 v4;
#pragma unroll
                    for (int r = 0; r < 4; r++) v4[r] = (bf16_t)acc[i][j][r];
                    *(bf16x4*)(Vt + (size_t)vcol * SEQ + mp) = v4;
                }
        }
    }
}

// ---- attention: 4 q-chunks x 2 key-halves, 64 q/wave, merge epilogue ----
__global__ __launch_bounds__(512, 2) void attn_kernel(const bf16_t* __restrict__ Q,
                                                      const bf16_t* __restrict__ Km,
                                                      const bf16_t* __restrict__ Vt,
                                                      bf16_t* __restrict__ O) {
    const int tid = threadIdx.x;
    const int lane = tid & 63;
    const int wave = tid >> 6;   // 0..7
    const int gw   = wave & 3;   // q-chunk: rows gw*64..gw*64+63
    const int grp  = wave >> 2;  // 0: keys 0..2047, 1: keys 2048..4095
    const int l15 = lane & 15;
    const int lg  = lane >> 4;
    const int bid = blockIdx.x;
    const int h    = (bid & 7) * 2 + ((bid >> 3) & 1);  // 2 heads/XCD
    const int qblk = bid >> 4;   // 0..15
    const int q0 = qblk * 256;
    const int hoff = h * DK;

    __shared__ union {
        struct {
            __align__(16) bf16_t Klo[2][64 * 64];
            __align__(16) bf16_t Vlo[2][64 * 64];
            __align__(16) bf16_t Khi[2][64 * 64];
            __align__(16) bf16_t Vhi[2][64 * 64];
        } kv;
        float scratch[4][64][68];   // padded stride 68 -> conflict-free
    } sm;
    __shared__ float lsum[4][64];

    bf16x8 qf[4][2];
#pragma unroll
    for (int t = 0; t < 4; t++)
#pragma unroll
        for (int c = 0; c < 2; c++)
            qf[t][c] = *(const bf16x8*)(Q + (size_t)(q0 + gw * 64 + t * 16 + l15) * D_MODEL
                                        + hoff + c * 32 + lg * 8);

    f32x4 oacc[4][4], lfrag[4];
#pragma unroll
    for (int t = 0; t < 4; t++) {
        lfrag[t] = f32x4{0.f, 0.f, 0.f, 0.f};
#pragma unroll
        for (int dt = 0; dt < 4; dt++) oacc[t][dt] = f32x4{0.f, 0.f, 0.f, 0.f};
    }

    bf16x8 ones8;
#pragma unroll
    for (int j = 0; j < 8; j++) ones8[j] = (bf16_t)1.0f;

    // staging (R14 mapping, applied to 4 tiles: lo/hi x K/V)
    const int srow = tid >> 3;
    const int sdc = (tid & 7) ^ (srow & 7);
    const bf16_t* kSrc = Km + (size_t)srow * D_MODEL + hoff + sdc * 8;
    const bf16_t* vSrc = Vt + (size_t)(hoff + srow) * SEQ + sdc * 8;
    const size_t kHi = (size_t)32 * 64 * D_MODEL;  // +2048 keys
    const int    vHi = 2048;

    int kOff[4][2], vOff[2][4];
#pragma unroll
    for (int kt = 0; kt < 4; kt++)
#pragma unroll
        for (int c = 0; c < 2; c++) {
            int row = kt * 16 + l15;
            kOff[kt][c] = row * 64 + (((c * 4 + lg) ^ (row & 7)) * 8);
        }
#pragma unroll
    for (int kp = 0; kp < 2; kp++)
#pragma unroll
        for (int dt = 0; dt < 4; dt++) {
            int row = dt * 16 + l15;
            vOff[kp][dt] = row * 64 + (((kp * 4 + lg) ^ (row & 7)) * 8);
        }

    // prologue: stage step 0 (both halves) into buffer 0
    g2l16(kSrc,       &sm.kv.Klo[0][tid * 8]);
    g2l16(vSrc,       &sm.kv.Vlo[0][tid * 8]);
    g2l16(kSrc + kHi, &sm.kv.Khi[0][tid * 8]);
    g2l16(vSrc + vHi, &sm.kv.Vhi[0][tid * 8]);

    for (int s = 0; s < 32; s++) {
        const int cur = s & 1;
        __syncthreads();

        if (s + 1 < 32) {
            const int nxt = cur ^ 1;
            const size_t ko = (size_t)(s + 1) * 64 * D_MODEL;
            const int    vo = (s + 1) * 64;
            g2l16(kSrc + ko,       &sm.kv.Klo[nxt][tid * 8]);
            g2l16(vSrc + vo,       &sm.kv.Vlo[nxt][tid * 8]);
            g2l16(kSrc + kHi + ko, &sm.kv.Khi[nxt][tid * 8]);
            g2l16(vSrc + vHi + vo, &sm.kv.Vhi[nxt][tid * 8]);
        }

        const bf16_t* Kb = grp ? sm.kv.Khi[cur] : sm.kv.Klo[cur];
        const bf16_t* Vb = grp ? sm.kv.Vhi[cur] : sm.kv.Vlo[cur];

#pragma unroll
        for (int kp = 0; kp < 2; kp++) {
            bf16x8 vf[4];
#pragma unroll
            for (int dt = 0; dt < 4; dt++) vf[dt] = *(const bf16x8*)(Vb + vOff[kp][dt]);

            f32x4 st[4][2];
#pragma unroll
            for (int sub = 0; sub < 2; sub++) {
                const int kt = kp * 2 + sub;
                const bf16x8 kf0 = *(const bf16x8*)(Kb + kOff[kt][0]);
                const bf16x8 kf1 = *(const bf16x8*)(Kb + kOff[kt][1]);
#pragma unroll
                for (int t = 0; t < 4; t++) {
                    f32x4 a = f32x4{0.f, 0.f, 0.f, 0.f};
                    a = __builtin_amdgcn_mfma_f32_16x16x32_bf16(kf0, qf[t][0], a, 0, 0, 0);
                    a = __builtin_amdgcn_mfma_f32_16x16x32_bf16(kf1, qf[t][1], a, 0, 0, 0);
                    st[t][sub] = a;
                }
            }

#pragma unroll
            for (int t = 0; t < 4; t++) {
                const bf16x8 pbig = exp2_pk(st[t][0], st[t][1]);
                lfrag[t] = __builtin_amdgcn_mfma_f32_16x16x32_bf16(ones8, pbig, lfrag[t], 0, 0, 0);
#pragma unroll
                for (int dt = 0; dt < 4; dt++)
                    oacc[t][dt] = __builtin_amdgcn_mfma_f32_16x16x32_bf16(vf[dt], pbig, oacc[t][dt], 0, 0, 0);
            }
        }
    }

    // ---- merge epilogue: hi waves publish partials; lo waves combine ----
    __syncthreads();   // all kv reads done; safe to reuse union as scratch
    if (grp == 1) {
#pragma unroll
        for (int t = 0; t < 4; t++) {
#pragma unroll
            for (int dt = 0; dt < 4; dt++)
                *(f32x4*)&sm.scratch[gw][t * 16 + l15][dt * 16 + lg * 4] = oacc[t][dt];
            if (lg == 0) lsum[gw][t * 16 + l15] = lfrag[t][0];
        }
    }
    __syncthreads();
    if (grp == 0) {
#pragma unroll
        for (int t = 0; t < 4; t++) {
            const float l = lfrag[t][0] + lsum[gw][t * 16 + l15];
            const float inv = 1.f / l;
            const size_t qrow = (size_t)(q0 + gw * 64 + t * 16 + l15);
#pragma unroll
            for (int dt = 0; dt < 4; dt++) {
                f32x4 oh = *(const f32x4*)&sm.scratch[gw][t * 16 + l15][dt * 16 + lg * 4];
                bf16x4 o4;
#pragma unroll
                for (int r = 0; r < 4; r++) o4[r] = (bf16_t)((oacc[t][dt][r] + oh[r]) * inv);
                *(bf16x4*)(O + qrow * D_MODEL + hoff + dt * 16 + lg * 4) = o4;
            }
        }
    }
}

// ---------------- launcher ----------------
extern "C" void kernel_launch(void* const* d_in, const int* in_sizes, int n_in,
                              void* d_out, int out_size, void* d_ws, size_t ws_size,
                              hipStream_t stream) {
    const float* x  = (const float*)d_in[0];
    const float* Wq = (const float*)d_in[1];
    const float* Wk = (const float*)d_in[2];
    const float* Wv = (const float*)d_in[3];
    const float* Wo = (const float*)d_in[4];
    float* out = (float*)d_out;

    char* ws = (char*)d_ws;
    bf16_t* xb  = (bf16_t*)(ws);
    bf16_t* wqb = (bf16_t*)(ws + (8u  << 20));
    bf16_t* wob = (bf16_t*)(ws + (14u << 20));
    bf16_t* Qb  = (bf16_t*)(ws + (16u << 20));
    bf16_t* Kb  = (bf16_t*)(ws + (24u << 20));
    bf16_t* Vtb = (bf16_t*)(ws + (32u << 20));
    bf16_t* Ab  = (bf16_t*)(ws + (40u << 20));

    // fused cast: 1M threads for x (4M elems) + 1M for the 4 weights
    cast_all<<<8192, 256, 0, stream>>>(x, Wq, Wk, Wv, Wo, xb, wqb);

    gemm_lds<1><<<dim3(3 * D_MODEL / 128, SEQ / 128), 256, 0, stream>>>(
        xb, wqb, Qb, Kb, Vtb, SEQ, 3 * D_MODEL, D_MODEL);

    attn_kernel<<<256, 512, 0, stream>>>(Qb, Kb, Vtb, Ab);

    gemm_lds<0><<<dim3(D_MODEL / 128, SEQ / 128), 256, 0, stream>>>(
        Ab, wob, out, nullptr, nullptr, SEQ, D_MODEL, D_MODEL);
}